// Round 4
// 405.782 us; speedup vs baseline: 1.3303x; 1.3303x over previous
//
#include <hip/hip_runtime.h>
#include <hip/hip_bf16.h>

#define B_  16
#define C_  64
#define H_  128
#define W_  128
#define HW_ (H_*W_)
#define E_  8

// ws layout (float offsets)
#define WS_LOGITS 0       // 128 floats
#define WS_SEL    128     // 32 ints: e1[16] then e2[16]
#define WS_R      160     // kept for the ws_size check only

// ---- sentinel: encode a failed host-side assertion in the absmax ----
__global__ void k_sentinel(float* out, float v){
    if (blockIdx.x == 0 && threadIdx.x == 0) out[0] = v;
}

// ================= k1p: router conv, channel-split partials =================
// 16x64 pixel tile, 4 channel groups of 16 channels (1024 blocks, 4/CU).
// Double-buffered LDS staging; float4/float2 LDS window reads.
// Partial r for group g goes to part[g*B*HW + b*HW + hw]  (part = d_out scratch).
#define R_TH 16
#define R_TW 64
#define R_HH (R_TH+6)    // 22
#define R_HW (R_TW+6)    // 70
#define R_LS 76          // LDS row stride (x4B, 16B-aligned rows)
#define R_HN (R_HH*R_HW) // 1540
#define RG_CH 16         // channels per group
#define RG_N  4          // groups

__device__ __forceinline__ void r_stage(const float* __restrict__ xc, float* dst,
                                        int row0, int col0, int tid){
    for (int i = tid; i < R_HN; i += 256){
        int hr = i / R_HW, hc = i - hr*R_HW;
        int gr = row0 + hr - 3, gc = col0 + hc - 3;
        float v = 0.f;
        if ((unsigned)gr < (unsigned)H_ && (unsigned)gc < (unsigned)W_)
            v = xc[gr*W_+gc];
        dst[hr*R_LS+hc] = v;
    }
}

__global__ __launch_bounds__(256) void k1p(const float* __restrict__ x,
                                           const float* __restrict__ rw,
                                           const float* __restrict__ rb,
                                           float* __restrict__ part){
    __shared__ __align__(16) float tile[2][R_HH*R_LS];   // 2 x 6688 B

    int id = blockIdx.x;
    int g   = id & 3; id >>= 2;      // channel group
    int txt = id & 1; id >>= 1;      // col half
    int tyt = id & 7; id >>= 3;      // 16-row band
    int b   = id;                    // 16
    int row0 = tyt*R_TH, col0 = txt*R_TW;
    int tx = threadIdx.x & 15, ty = threadIdx.x >> 4;
    int row  = row0 + ty;
    int colb = col0 + 4*tx;

    const float* xg  = x  + ((size_t)(b*C_) + g*RG_CH)*HW_;
    const float* wgr = rw + g*RG_CH*49;

    float acc[4] = {0.f,0.f,0.f,0.f};

    r_stage(xg, tile[0], row0, col0, threadIdx.x);
    __syncthreads();

    for (int ch = 0; ch < RG_CH; ++ch){
        if (ch + 1 < RG_CH)
            r_stage(xg + (size_t)(ch+1)*HW_, tile[(ch+1)&1], row0, col0, threadIdx.x);

        const float* wr = wgr + ch*49;           // block-uniform -> SGPR
        const float* tb = tile[ch&1];
        #pragma unroll
        for (int ky = 0; ky < 7; ++ky){
            const float* trow = &tb[(ty+ky)*R_LS + 4*tx];
            float4 va = *(const float4*)(trow);
            float4 vb = *(const float4*)(trow+4);
            float2 vc = *(const float2*)(trow+8);
            float win[10] = {va.x,va.y,va.z,va.w, vb.x,vb.y,vb.z,vb.w, vc.x,vc.y};
            #pragma unroll
            for (int kx = 0; kx < 7; ++kx){
                float w = wr[ky*7+kx];
                acc[0] += w*win[kx+0];
                acc[1] += w*win[kx+1];
                acc[2] += w*win[kx+2];
                acc[3] += w*win[kx+3];
            }
        }
        __syncthreads();
    }

    if (g == 0){
        float rbv = rb[0];
        acc[0]+=rbv; acc[1]+=rbv; acc[2]+=rbv; acc[3]+=rbv;
    }
    float* pr = part + (size_t)g*(B_*HW_);
    size_t base = (size_t)b*HW_ + (size_t)row*W_ + colb;
    #pragma unroll
    for (int p = 0; p < 4; ++p) pr[base+p] = acc[p];
}

// ---- kg: logits[b,e] = sum_hw (sum_g part[g,b,hw]) * wg[hw,e] ----
__global__ __launch_bounds__(256) void kg(const float* __restrict__ part,
                                          const float* __restrict__ wg,
                                          float* __restrict__ logits){
    __shared__ float red[256];
    int b = blockIdx.x >> 3, e = blockIdx.x & 7;   // 128 blocks
    const float* p0 = part + (size_t)b*HW_;
    const float* p1 = p0 + 1*(size_t)(B_*HW_);
    const float* p2 = p0 + 2*(size_t)(B_*HW_);
    const float* p3 = p0 + 3*(size_t)(B_*HW_);
    float s = 0.f;
    for (int hw = threadIdx.x; hw < HW_; hw += 256){
        float rv = p0[hw] + p1[hw] + p2[hw] + p3[hw];
        s += rv * wg[(size_t)hw*E_ + e];
    }
    red[threadIdx.x] = s;
    __syncthreads();
    for (int off = 128; off > 0; off >>= 1){
        if (threadIdx.x < off) red[threadIdx.x] += red[threadIdx.x + off];
        __syncthreads();
    }
    if (threadIdx.x == 0) logits[b*E_+e] = red[0];
}

// ---- k2: single-thread top-2 gating + loss ----
__global__ void k2_gating(const float* __restrict__ logits,
                          int* __restrict__ sel,
                          float* __restrict__ out){
    if (threadIdx.x != 0 || blockIdx.x != 0) return;
    float imp[E_]; int cnt[E_];
    for (int e = 0; e < E_; ++e){ imp[e] = 0.f; cnt[e] = 0; }
    for (int b = 0; b < B_; ++b){
        const float* l = logits + b*E_;
        int i1 = 0;
        for (int e = 1; e < E_; ++e) if (l[e] > l[i1]) i1 = e;   // ties -> lowest idx
        int i2 = (i1 == 0) ? 1 : 0;
        for (int e = 0; e < E_; ++e) if (e != i1 && l[e] > l[i2]) i2 = e;
        float ex = expf(l[i2] - l[i1]);
        float g1 = 1.f/(1.f+ex), g2 = ex/(1.f+ex);
        sel[b] = i1; sel[B_ + b] = i2;
        imp[i1] += g1; imp[i2] += g2; cnt[i1] += 1; cnt[i2] += 1;
    }
    float m1 = 0.f, m2 = 0.f;
    for (int e = 0; e < E_; ++e){ m1 += imp[e]; m2 += (float)cnt[e]; }
    m1 *= (1.f/E_); m2 *= (1.f/E_);
    float v1 = 0.f, v2 = 0.f;
    for (int e = 0; e < E_; ++e){
        float d1 = imp[e] - m1;        v1 += d1*d1;
        float d2 = (float)cnt[e] - m2; v2 += d2*d2;
    }
    v1 *= (1.f/(E_-1)); v2 *= (1.f/(E_-1));
    float loss = (v1/(m1*m1 + 1e-10f) + v2/(m2*m2 + 1e-10f)) * 0.01f;
    out[(size_t)B_*HW_*C_] = loss;
}

// ================= k3: tiled experts+shared conv + LSE combine =================
// 16x16 pixel tile, 4 chunks of 16 channels. Padded LDS strides so all window
// and weight reads are aligned float4 (ds_read_b128), bank-quad balanced.
#define T3     16
#define H3     (T3+6)          // 22
#define CS3    28              // LDS col stride (22 used, mult of 4)
#define CHS3   (H3*CS3)        // 616 floats per channel plane
#define NCH3   16              // channels per chunk
#define WST3   56              // weight stride per channel: 7 ky x 8 (kx 0..6 + pad)

__global__ __launch_bounds__(256) void k3_tiled(const float* __restrict__ x,
                                                const float* __restrict__ ew,
                                                const float* __restrict__ eb,
                                                const float* __restrict__ sw,
                                                const float* __restrict__ sb,
                                                const int* __restrict__ sel,
                                                float* __restrict__ out){
    __shared__ __align__(16) float tile[NCH3*CHS3];     // 9856 floats = 39.4 KB
    __shared__ __align__(16) float wbuf[3*NCH3*WST3];   // 2688 floats = 10.8 KB

    int id = blockIdx.x;
    int cx = id & 7; id >>= 3;
    int cy = id & 7; id >>= 3;
    int b  = id;                           // 1024 blocks
    int r0 = cy*T3, c0 = cx*T3;

    int c16  = threadIdx.x & 15;           // channel within chunk
    int trow = threadIdx.x >> 4;           // tile row [0,16)

    int e1 = sel[b], e2 = sel[B_ + b];

    for (int chunk = 0; chunk < 4; ++chunk){
        int cc0 = chunk*NCH3;
        __syncthreads();
        // stage x: 16 ch x 22 x 22 (stride-28 rows)
        for (int i = threadIdx.x; i < NCH3*H3*H3; i += 256){
            int ci = i / (H3*H3);
            int rem = i - ci*(H3*H3);
            int hr = rem / H3, hc = rem - hr*H3;
            int gr = r0 + hr - 3, gc = c0 + hc - 3;
            float v = 0.f;
            if ((unsigned)gr < (unsigned)H_ && (unsigned)gc < (unsigned)W_)
                v = x[((size_t)(b*C_ + cc0 + ci))*HW_ + gr*W_ + gc];
            tile[ci*CHS3 + hr*CS3 + hc] = v;
        }
        // stage weights: 3 x 16ch x (7ky x 8), kx==7 slot zero-padded
        for (int i = threadIdx.x; i < 3*NCH3*WST3; i += 256){
            int which = i / (NCH3*WST3);
            int rem = i - which*(NCH3*WST3);
            int wc = rem / WST3;
            int t  = rem - wc*WST3;
            int ky = t >> 3, kx = t & 7;
            float v = 0.f;
            if (kx < 7){
                int tap = ky*7 + kx;
                if (which == 0)      v = ew[((size_t)(e1*C_ + cc0 + wc))*49 + tap];
                else if (which == 1) v = ew[((size_t)(e2*C_ + cc0 + wc))*49 + tap];
                else                 v = sw[((size_t)(cc0 + wc))*49 + tap];
            }
            wbuf[i] = v;
        }
        __syncthreads();

        float acc1[T3], acc2[T3], acc3[T3];
        #pragma unroll
        for (int j = 0; j < T3; ++j){ acc1[j]=0.f; acc2[j]=0.f; acc3[j]=0.f; }

        const float* tbase = &tile[c16*CHS3];
        const float* w1 = &wbuf[(0*NCH3 + c16)*WST3];
        const float* w2 = &wbuf[(1*NCH3 + c16)*WST3];
        const float* w3 = &wbuf[(2*NCH3 + c16)*WST3];

        #pragma unroll
        for (int ky = 0; ky < 7; ++ky){
            const float* trp = tbase + (trow+ky)*CS3;
            float win[22];
            #pragma unroll
            for (int q = 0; q < 5; ++q){
                float4 v = *(const float4*)(trp + 4*q);
                win[4*q+0]=v.x; win[4*q+1]=v.y; win[4*q+2]=v.z; win[4*q+3]=v.w;
            }
            { float2 v = *(const float2*)(trp + 20); win[20]=v.x; win[21]=v.y; }

            float u1[7], u2[7], u3[7];
            { float4 a = *(const float4*)(w1 + ky*8);
              float4 c = *(const float4*)(w1 + ky*8 + 4);
              u1[0]=a.x;u1[1]=a.y;u1[2]=a.z;u1[3]=a.w;u1[4]=c.x;u1[5]=c.y;u1[6]=c.z; }
            { float4 a = *(const float4*)(w2 + ky*8);
              float4 c = *(const float4*)(w2 + ky*8 + 4);
              u2[0]=a.x;u2[1]=a.y;u2[2]=a.z;u2[3]=a.w;u2[4]=c.x;u2[5]=c.y;u2[6]=c.z; }
            { float4 a = *(const float4*)(w3 + ky*8);
              float4 c = *(const float4*)(w3 + ky*8 + 4);
              u3[0]=a.x;u3[1]=a.y;u3[2]=a.z;u3[3]=a.w;u3[4]=c.x;u3[5]=c.y;u3[6]=c.z; }

            #pragma unroll
            for (int col = 0; col < T3; ++col){
                #pragma unroll
                for (int kx = 0; kx < 7; ++kx){
                    float xv = win[col+kx];
                    acc1[col] += u1[kx]*xv;
                    acc2[col] += u2[kx]*xv;
                    acc3[col] += u3[kx]*xv;
                }
            }
        }

        float b1 = eb[e1*C_ + cc0 + c16];
        float b2 = eb[e2*C_ + cc0 + c16];
        float b3 = sb[cc0 + c16];
        size_t obase = ((size_t)b*HW_ + (size_t)(r0+trow)*W_ + c0)*C_ + cc0 + c16;
        #pragma unroll
        for (int col = 0; col < T3; ++col){
            float o1 = acc1[col] + b1;
            float o2 = acc2[col] + b2;
            float o3 = acc3[col] + b3;
            float v = __expf(o1) + __expf(o2);
            if (v == 0.f) v = 2.220446049250313e-16f;
            out[obase + (size_t)col*C_] = __logf(v) + o3;
        }
    }
}

extern "C" void kernel_launch(void* const* d_in, const int* in_sizes, int n_in,
                              void* d_out, int out_size, void* d_ws, size_t ws_size,
                              hipStream_t stream) {
    float* out = (float*)d_out;

    // ---- host-side assumption assertions -> sentinel in absmax ----
    static const int exp_sizes[8] = {16777216, 3136, 1, 131072, 25088, 512, 3136, 64};
    if (n_in != 8){ k_sentinel<<<1,64,0,stream>>>(out, 500.f); return; }
    for (int i = 0; i < 8; ++i){
        if (in_sizes[i] != exp_sizes[i]){
            k_sentinel<<<1,64,0,stream>>>(out, 600.f + 8.f*i); return;
        }
    }
    if (out_size != 16777217){ k_sentinel<<<1,64,0,stream>>>(out, 800.f); return; }
    if (ws_size < (size_t)(WS_SEL + 64)*4){ k_sentinel<<<1,64,0,stream>>>(out, 900.f); return; }

    const float* x  = (const float*)d_in[0];
    const float* rw = (const float*)d_in[1];
    const float* rb = (const float*)d_in[2];
    const float* wg = (const float*)d_in[3];
    const float* ew = (const float*)d_in[4];
    const float* eb = (const float*)d_in[5];
    const float* sw = (const float*)d_in[6];
    const float* sb = (const float*)d_in[7];
    float* wsf = (float*)d_ws;

    // Partial router outputs live in d_out (fully overwritten by k3 afterwards):
    // part[g][b][hw], g=0..3  -> 4 MB of the 64 MB output buffer.
    k1p<<<1024, 256, 0, stream>>>(x, rw, rb, out);
    kg<<<128, 256, 0, stream>>>(out, wg, wsf + WS_LOGITS);
    k2_gating<<<1, 64, 0, stream>>>(wsf + WS_LOGITS, (int*)(wsf + WS_SEL), out);
    k3_tiled<<<1024, 256, 0, stream>>>(x, ew, eb, sw, sb,
                                       (const int*)(wsf + WS_SEL), out);
}